// Round 7
// baseline (542.512 us; speedup 1.0000x reference)
//
#include <hip/hip_runtime.h>
#include <hip/hip_bf16.h>

typedef __hip_bfloat16 bf16;
typedef short v8s __attribute__((ext_vector_type(8)));     // 8 bf16 (4 VGPRs)
typedef float f32x4 __attribute__((ext_vector_type(4)));   // MFMA acc

#define B_  32
#define L_  144
#define D_  96
#define HW_ 64

#define PIXSTRIDE 80             // 32 l * 2B = 64B data + 16B pad (bank spread)
#define WPACK_ELEMS (83*5*96*32) // packed bf16 weights

__device__ __forceinline__ unsigned short f2bf(float f) {
    union { float f; unsigned int u; } x{f};
    unsigned int r = x.u + 0x7fffu + ((x.u >> 16) & 1u);   // RNE
    return (unsigned short)(r >> 16);
}
__device__ __forceinline__ float bf2f(unsigned short u) {
    union { unsigned int u; float f; } x{(unsigned int)u << 16};
    return x.f;
}

// ---------------------------------------------------------------------------
// Weight prep: pack w1/w2/w3 (fp32, [D][L][k][k]) into A-fragment order bf16:
// wpack[((T*5+q)*96 + d)*32 + l~],  T: 0..48=7x7 taps, 49..73=5x5, 74..82=3x3,
// q = l-chunk (l = q*32+l~, zero-padded past 143).
// ---------------------------------------------------------------------------
__global__ __launch_bounds__(256) void prep_weights(
    const float* __restrict__ w1, const float* __restrict__ w2,
    const float* __restrict__ w3, unsigned short* __restrict__ wpack)
{
    int i = blockIdx.x * 256 + threadIdx.x;
    if (i >= WPACK_ELEMS) return;
    const int lt = i & 31;
    const int d  = (i >> 5) % 96;
    const int r  = (i >> 5) / 96;   // T*5 + q
    const int q  = r % 5;
    const int T  = r / 5;
    const int l  = q * 32 + lt;
    float v = 0.f;
    if (l < L_) {
        if (T < 49)      v = w3[(d * L_ + l) * 49 + T];
        else if (T < 74) v = w2[(d * L_ + l) * 25 + (T - 49)];
        else             v = w1[(d * L_ + l) * 9  + (T - 74)];
    }
    wpack[i] = f2bf(v);
}

// ---------------------------------------------------------------------------
// Single-branch MFMA conv, templated on kernel size. Block: 96 d x (16x16 px),
// 8 waves = 2 d-halves x 4 px-quads; wave = 3 d-tiles x 4 px-rows x 1 branch
// = 12 accs (~<=128 unified regs -> 2 blocks/CU, 4 waves/SIMD).
// MODE 0: write y=BN+ReLU(conv) bf16 -> slot upper half   (7x7 / y3)
// MODE 1: write y bf16 -> slot lower half                 (5x5 / y2)
// MODE 2: y1 = BN+ReLU(conv); read y2 (lower), y3 (upper);
//         add -> lower, max -> upper                      (3x3 / combine)
// ---------------------------------------------------------------------------
template<int KSZ, int TBASE, int MODE>
__global__ __launch_bounds__(512, 4) void conv_branch(
    const float* __restrict__ x, const unsigned short* __restrict__ wpack,
    const float* __restrict__ bb, const float* __restrict__ gg,
    const float* __restrict__ bbe, const float* __restrict__ mm,
    const float* __restrict__ vv,
    float* __restrict__ outp)
{
    constexpr int PAD  = KSZ / 2;
    constexpr int PXR  = 16 + 2 * PAD;    // patch rows/cols
    constexpr int NPIX = PXR * PXR;
    constexpr int NP   = NPIX * 32;       // staged elements per l-chunk

    __shared__ __align__(16) unsigned char patchB[NPIX * PIXSTRIDE];
    __shared__ float bns[96 * 2];

    const int t    = threadIdx.x;
    const int lane = t & 63;
    const int wid  = t >> 6;           // 0..7
    const int dhalf = wid >> 2;        // 0..1
    const int ptb   = (wid & 3) * 4;   // px-quad base row
    const int lo = lane & 15;
    const int hi = lane >> 4;

    const int st = blockIdx.x;
    const int h0 = (st >> 2) << 4;
    const int w0 = (st & 3) << 4;
    const int b  = blockIdx.y;

    const int laneBoff = lo * PIXSTRIDE + hi * 16;
    const int laneAoff = lo * 32 + hi * 8;

    if (t < 96) {
        const float iv = gg[t] * rsqrtf(vv[t] + 1e-5f);
        bns[t*2+0] = iv;
        bns[t*2+1] = fmaf(bb[t] - mm[t], iv, bbe[t]);
    }

    f32x4 acc[3][4];
    #pragma unroll
    for (int dt = 0; dt < 3; ++dt)
        #pragma unroll
        for (int pp = 0; pp < 4; ++pp) acc[dt][pp] = (f32x4)0.f;

    const unsigned short* wqBase = wpack + dhalf * 1536 + laneAoff;

    for (int q = 0; q < 5; ++q) {
        __syncthreads();
        // ---- stage patch chunk q: [pixel][32 l] bf16 ----
        for (int i = t; i < NP; i += 512) {
            const int l   = i / NPIX;
            const int pix = i - l * NPIX;
            const int r = pix / PXR, c = pix - r * PXR;
            const int gh = h0 - PAD + r, gw = w0 - PAD + c;
            const int lg = q * 32 + l;
            float v = 0.f;
            if (lg < L_ && (unsigned)gh < 64u && (unsigned)gw < 64u)
                v = x[(((size_t)b * L_ + lg) << 12) + (gh << 6) + gw];
            *(unsigned short*)(patchB + pix * PIXSTRIDE + l * 2) = f2bf(v);
        }
        __syncthreads();

        const unsigned short* wq = wqBase + q * 3072;

        for (int kh = 0; kh < KSZ; ++kh) {
            const int rb0 = (ptb + kh) * PXR;
            #pragma unroll
            for (int kw = 0; kw < KSZ; ++kw) {
                v8s Bv[4];
                #pragma unroll
                for (int pp = 0; pp < 4; ++pp)
                    Bv[pp] = *(const v8s*)(patchB + (rb0 + pp * PXR + kw) * PIXSTRIDE + laneBoff);

                const unsigned short* wp = wq + (TBASE + kh * KSZ + kw) * 15360;
                const v8s A0 = *(const v8s*)(wp);
                const v8s A1 = *(const v8s*)(wp + 512);
                const v8s A2 = *(const v8s*)(wp + 1024);
                #pragma unroll
                for (int pp = 0; pp < 4; ++pp) {
                    acc[0][pp] = __builtin_amdgcn_mfma_f32_16x16x32_bf16(A0, Bv[pp], acc[0][pp], 0, 0, 0);
                    acc[1][pp] = __builtin_amdgcn_mfma_f32_16x16x32_bf16(A1, Bv[pp], acc[1][pp], 0, 0, 0);
                    acc[2][pp] = __builtin_amdgcn_mfma_f32_16x16x32_bf16(A2, Bv[pp], acc[2][pp], 0, 0, 0);
                }
            }
        }
    }

    // ---- epilogue ----
    #pragma unroll
    for (int dt = 0; dt < 3; ++dt) {
        #pragma unroll
        for (int reg = 0; reg < 4; ++reg) {
            const int d = dhalf * 48 + dt * 16 + hi * 4 + reg;
            const float iv = bns[d*2+0], cv = bns[d*2+1];
            unsigned short* pl = (unsigned short*)(outp + (((size_t)b * D_ + d) << 12));
            #pragma unroll
            for (int pp = 0; pp < 4; ++pp) {
                const float y = fmaxf(0.f, fmaf(acc[dt][pp][reg], iv, cv));
                const int idx = ((h0 + ptb + pp) << 6) + w0 + lo;
                if constexpr (MODE == 0) {
                    pl[4096 + idx] = f2bf(y);
                } else if constexpr (MODE == 1) {
                    pl[idx] = f2bf(y);
                } else {
                    const float y2 = bf2f(pl[idx]);
                    const float y3 = bf2f(pl[4096 + idx]);
                    const float av = y + y2 + y3;
                    const float mv = fmaxf(y, fmaxf(y2, y3));
                    pl[idx]        = f2bf(av);
                    pl[4096 + idx] = f2bf(mv);
                }
            }
        }
    }
}

// ---------------------------------------------------------------------------
// Kernel B: per-plane 3x3 conv over [add; max] with avg folded (unchanged).
// ---------------------------------------------------------------------------
__global__ __launch_bounds__(256) void fuse_kernel(
    const float* __restrict__ wf, float* __restrict__ out)
{
    const int p = blockIdx.x;      // plane = b*96 + d
    const int t = threadIdx.x;
    __shared__ float sa[66 * 66];
    __shared__ float sm[66 * 66];
    const bf16* base = (const bf16*)(out + ((size_t)p << 12));

    for (int i = t; i < 66 * 66; i += 256) {
        const int c = i % 66, r = i / 66;
        const int gh = r - 1, gw = c - 1;
        float va = 0.f, vm = 0.f;
        if (gh >= 0 && gh < 64 && gw >= 0 && gw < 64) {
            va = __bfloat162float(base[(gh << 6) + gw]);
            vm = __bfloat162float(base[4096 + (gh << 6) + gw]);
        }
        sa[i] = va; sm[i] = vm;
    }

    float wa[9], wm[9];
    #pragma unroll
    for (int j = 0; j < 9; ++j) {
        wa[j] = wf[j] + wf[9 + j] * (1.f / 3.f);
        wm[j] = wf[18 + j];
    }
    __syncthreads();

    float* op = out + ((size_t)p << 12);
    for (int i = t; i < 4096; i += 256) {
        const int h = i >> 6, w = i & 63;
        float acc = 0.f;
        #pragma unroll
        for (int kh = 0; kh < 3; ++kh) {
            #pragma unroll
            for (int kw = 0; kw < 3; ++kw) {
                acc = fmaf(sa[(h + kh) * 66 + (w + kw)], wa[kh * 3 + kw], acc);
                acc = fmaf(sm[(h + kh) * 66 + (w + kw)], wm[kh * 3 + kw], acc);
            }
        }
        op[i] = acc;
    }
}

extern "C" void kernel_launch(void* const* d_in, const int* in_sizes, int n_in,
                              void* d_out, int out_size, void* d_ws, size_t ws_size,
                              hipStream_t stream)
{
    const float* x   = (const float*)d_in[0];
    const float* w1  = (const float*)d_in[1];
    const float* b1  = (const float*)d_in[2];
    const float* g1  = (const float*)d_in[3];
    const float* be1 = (const float*)d_in[4];
    const float* m1  = (const float*)d_in[5];
    const float* v1  = (const float*)d_in[6];
    const float* w2  = (const float*)d_in[7];
    const float* b2  = (const float*)d_in[8];
    const float* g2  = (const float*)d_in[9];
    const float* be2 = (const float*)d_in[10];
    const float* m2  = (const float*)d_in[11];
    const float* v2  = (const float*)d_in[12];
    const float* w3  = (const float*)d_in[13];
    const float* b3  = (const float*)d_in[14];
    const float* g3  = (const float*)d_in[15];
    const float* be3 = (const float*)d_in[16];
    const float* m3  = (const float*)d_in[17];
    const float* v3  = (const float*)d_in[18];
    const float* wf  = (const float*)d_in[19];
    float* out = (float*)d_out;

    // d_ws: packed bf16 weights only (2.55 MB, proven safe rounds 4-6)
    unsigned short* wpack = (unsigned short*)d_ws;

    prep_weights<<<(WPACK_ELEMS + 255) / 256, 256, 0, stream>>>(w1, w2, w3, wpack);

    dim3 gridA(16, B_);   // 16 spatial tiles x 32 batch
    // y3 -> upper half of each plane slot
    conv_branch<7, 0, 0><<<gridA, 512, 0, stream>>>(x, wpack, b3, g3, be3, m3, v3, out);
    // y2 -> lower half
    conv_branch<5, 49, 1><<<gridA, 512, 0, stream>>>(x, wpack, b2, g2, be2, m2, v2, out);
    // y1 + combine -> add (lower) / max (upper)
    conv_branch<3, 74, 2><<<gridA, 512, 0, stream>>>(x, wpack, b1, g1, be1, m1, v1, out);

    fuse_kernel<<<B_ * D_, 256, 0, stream>>>(wf, out);
}